// Round 15
// baseline (947.164 us; speedup 1.0000x reference)
//
#include <hip/hip_runtime.h>
#include <stdint.h>

// ---------------- types ----------------
typedef unsigned short u16;
typedef unsigned long long u64;
typedef __attribute__((ext_vector_type(8)))  short  bf16x8;   // 8 bf16 (MFMA A/B frag)
typedef __attribute__((ext_vector_type(8)))  u16    u16x8;
typedef __attribute__((ext_vector_type(4)))  float  f32x4;
typedef __attribute__((ext_vector_type(16))) _Float16 f16x16; // 32B chunk

#define MFMA_BF16(a,b,c) __builtin_amdgcn_mfma_f32_16x16x32_bf16((a),(b),(c),0,0,0)

// ---------------- problem constants ----------------
#define BATCH   2048
#define FSTEPS  32
#define RSTEPS  3
#define NVF     35            // 32 fwd virtual frames + 3 rev (63,62,61)

// h global buffers: [parity][2048 rows][128 u32] (256 bf16 cols packed in pairs)
static constexpr size_t HROW32 = 128;
static constexpr size_t HPAR32 = (size_t)BATCH * HROW32;

// ---------------- ws layout (bytes) ----------------
static constexpr size_t OFF_CTL  = 0;                                  // 32 KB flag lines (zeroed)
static constexpr size_t OFF_H0G  = 32768;                              // fwd h0: 2 MiB (2 parities)
static constexpr size_t OFF_H1G  = OFF_H0G + HPAR32 * 2 * 4;           // fwd h1
static constexpr size_t OFF_H0GR = OFF_H1G + HPAR32 * 2 * 4;           // rev h0
static constexpr size_t OFF_H1GR = OFF_H0GR + HPAR32 * 2 * 4;          // rev h1
static constexpr size_t OFF_LAT  = OFF_H1GR + HPAR32 * 2 * 4;          // latent fp32 (2048x512)
static constexpr size_t OFF_XP   = OFF_LAT + (size_t)BATCH * 512 * 4;  // xproj fp16 gather layout
static constexpr size_t XP_BYTES = (size_t)NVF * BATCH * 1024 * 2;     // [vf][rb128][m16][lane64][16]
static constexpr size_t OFF_W0XF = OFF_XP + XP_BYTES;                  // Wih0 row-major bf16 [1024][512]
static constexpr size_t OFF_W0XR = OFF_W0XF + (size_t)1024 * 512 * 2;
static constexpr size_t OFF_P0F  = OFF_W0XR + (size_t)1024 * 512 * 2;  // Whh0 frag-packed 512 KB
static constexpr size_t OFF_P0R  = OFF_P0F + (size_t)32768 * 16;
static constexpr size_t OFF_P1F  = OFF_P0R + (size_t)32768 * 16;       // W1 frag-packed 1 MB
static constexpr size_t OFF_P1R  = OFF_P1F + (size_t)65536 * 16;
static constexpr size_t OFF_BS0F = OFF_P1R + (size_t)65536 * 16;       // bias sums fp32 [1024]
static constexpr size_t OFF_BS0R = OFF_BS0F + 4096;
static constexpr size_t OFF_BS1F = OFF_BS0R + 4096;
static constexpr size_t OFF_BS1R = OFF_BS1F + 4096;
static constexpr size_t WS_NEED  = OFF_BS1R + 4096;                    // ~165 MB (r8 proved >=224 avail)

// ---------------- small helpers ----------------
__device__ __forceinline__ u16 f2bf(float f) {
    unsigned u = __float_as_uint(f);
    unsigned r = (u + 0x7fffu + ((u >> 16) & 1u)) >> 16;
    return (u16)r;
}
__device__ __forceinline__ float sigm(float x) { return 1.0f / (1.0f + __expf(-x)); }
__device__ __forceinline__ float tanh_fast(float x) {
    float a = fabsf(x);
    float e = __expf(-2.0f * a);
    float t = (1.0f - e) / (1.0f + e);
    return x < 0.0f ? -t : t;
}
__device__ __forceinline__ u16 f2h(float f) {   // fp32 -> fp16 bits
    _Float16 h = (_Float16)f;
    union { _Float16 h; u16 b; } u; u.h = h; return u.b;
}

// LDS h tile: [32 rows][256 bf16], row stride 512B, XOR swizzle on byte bits 4-6
__device__ __forceinline__ bf16x8 ldsA(const char* H, int row, int k) {
    int byte = (row << 9) + (k << 1);
    byte ^= (row & 7) << 4;
    return *(const bf16x8*)(H + byte);
}

// reload 32x256 h tile (16KB) from global parity buffer into LDS (sc1 u64 loads)
__device__ __forceinline__ void reload32(char* Hs, const u64* src, int rg, int tid) {
    u64 v[8];
#pragma unroll
    for (int i = 0; i < 8; ++i) {
        int idx = tid + (i << 8);                 // 0..2047
        v[i] = __hip_atomic_load(src + ((size_t)rg * 32 + (idx >> 6)) * 64 + (idx & 63),
                                 __ATOMIC_RELAXED, __HIP_MEMORY_SCOPE_AGENT);
    }
#pragma unroll
    for (int i = 0; i < 8; ++i) {
        int idx = tid + (i << 8);
        int row = idx >> 6, cu = idx & 63;
        int byte = (row << 9) + (cu << 3);
        byte ^= (row & 7) << 4;
        *(u64*)(Hs + byte) = v[i];
    }
}

// ---------------- persistent sequential kernel (r10 structure, rev FOLDED into fwd) ----------------
// 256 blocks x 256 thr (4 waves), 1 block/CU. Block = M=32 rows x 256 gate-cols.
// Decode: colq = bid>>6, rg = bid&63. Partners {rg,+64,+128,+192} share bid%8 -> same XCD.
// Wave wq -> weight slice mem = colq*4+wq. Merged phase layer1(t-1)+layer0(t).
// REV direction (3 steps) runs INSIDE fwd steps t=0..3 (independent state/weights;
// fills idle issue slots) -> 33 iterations / 32 barriers total (was 37 / 35).
__global__ void __launch_bounds__(256)
lstm_seq(const _Float16* __restrict__ xp,
         const u16* __restrict__ P0f_, const u16* __restrict__ P0r_,
         const u16* __restrict__ P1f_, const u16* __restrict__ P1r_,
         const float* __restrict__ bs1f, const float* __restrict__ bs1r,
         unsigned* __restrict__ h0g, unsigned* __restrict__ h1g,
         unsigned* __restrict__ h0gr, unsigned* __restrict__ h1gr,
         float* __restrict__ latent, unsigned* __restrict__ ctl)
{
    __shared__ char T0[16384];    // fwd h0 tile: 32 rows x 256 bf16, swizzled
    __shared__ char T1[16384];    // fwd h1 tile
    __shared__ char T0r[16384];   // rev h0 tile
    __shared__ char T1r[16384];   // rev h1 tile
    const int tid = threadIdx.x, wq = tid >> 6, lane = tid & 63;
    const int bid = blockIdx.x;
    const int colq = bid >> 6;                 // 0..3
    const int rg   = bid & 63;                 // 0..63
    const int mem  = colq * 4 + wq;            // 0..15 (weight slice / h-col-16-block)
    const int hc   = mem * 16 + (lane & 15);
    const int klane = lane >> 4, q4 = klane << 2;
    const int cp   = mem * 8 + ((lane & 15) >> 1);
    unsigned* flag = ctl + (size_t)rg * 64;    // 256B line per group
    unsigned bcount = 0;

    const bf16x8* P0vf = (const bf16x8*)P0f_ + (size_t)mem * (8 * 4 * 64);
    const bf16x8* P0vr = (const bf16x8*)P0r_ + (size_t)mem * (8 * 4 * 64);
    const bf16x8* P1vf = (const bf16x8*)P1f_ + (size_t)mem * (16 * 4 * 64);
    const bf16x8* P1vr = (const bf16x8*)P1r_ + (size_t)mem * (16 * 4 * 64);
    float b1f[4], b1r[4];
#pragma unroll
    for (int g = 0; g < 4; ++g) { b1f[g] = bs1f[g * 256 + hc]; b1r[g] = bs1r[g * 256 + hc]; }

    float c0f[2][4], c1f[2][4], c0r[2][4], c1r[2][4];
#pragma unroll
    for (int Mt = 0; Mt < 2; ++Mt)
#pragma unroll
        for (int r = 0; r < 4; ++r) {
            c0f[Mt][r] = 0.f; c1f[Mt][r] = 0.f; c0r[Mt][r] = 0.f; c1r[Mt][r] = 0.f;
        }

    // zero all 4 tiles (h(-1) = 0); 4096 f32x4 over 256 thr
    __syncthreads();
#pragma unroll
    for (int i = 0; i < 4; ++i) {
        ((f32x4*)T0)[i * 256 + tid]  = (f32x4){0.f, 0.f, 0.f, 0.f};
        ((f32x4*)T1)[i * 256 + tid]  = (f32x4){0.f, 0.f, 0.f, 0.f};
        ((f32x4*)T0r)[i * 256 + tid] = (f32x4){0.f, 0.f, 0.f, 0.f};
        ((f32x4*)T1r)[i * 256 + tid] = (f32x4){0.f, 0.f, 0.f, 0.f};
    }
    __syncthreads();

    // xq for t=0: fwd vf=0, rev vf=32
    f16x16 xqf[2], xqr[2];
#pragma unroll
    for (int Mt = 0; Mt < 2; ++Mt) {
        xqf[Mt] = *(const f16x16*)(xp + ((((size_t)0  * 128 + rg * 2 + Mt) * 16 + mem) * 64 + lane) * 16);
        xqr[Mt] = *(const f16x16*)(xp + ((((size_t)32 * 128 + rg * 2 + Mt) * 16 + mem) * 64 + lane) * 16);
    }

    for (int t = 0; t <= FSTEPS; ++t) {
        // ======== FWD layer1(t-1): acc1 = [h0(t-1) | h1(t-2)] @ W1^T ========
        f32x4 acc1[4][2];
        if (t >= 1) {
#pragma unroll
            for (int g = 0; g < 4; ++g) { acc1[g][0] = (f32x4){0.f,0.f,0.f,0.f}; acc1[g][1] = (f32x4){0.f,0.f,0.f,0.f}; }
#pragma unroll
            for (int kc = 0; kc < 8; ++kc) {
                bf16x8 a0 = ldsA(T0, (lane & 15),       kc * 32 + klane * 8);
                bf16x8 a1 = ldsA(T0, 16 + (lane & 15),  kc * 32 + klane * 8);
#pragma unroll
                for (int g = 0; g < 4; ++g) {
                    bf16x8 b = P1vf[(kc * 4 + g) * 64 + lane];
                    acc1[g][0] = MFMA_BF16(a0, b, acc1[g][0]);
                    acc1[g][1] = MFMA_BF16(a1, b, acc1[g][1]);
                }
            }
            if (t >= 2) {
#pragma unroll
                for (int kc = 0; kc < 8; ++kc) {
                    bf16x8 a0 = ldsA(T1, (lane & 15),      kc * 32 + klane * 8);
                    bf16x8 a1 = ldsA(T1, 16 + (lane & 15), kc * 32 + klane * 8);
#pragma unroll
                    for (int g = 0; g < 4; ++g) {
                        bf16x8 b = P1vf[((kc + 8) * 4 + g) * 64 + lane];
                        acc1[g][0] = MFMA_BF16(a0, b, acc1[g][0]);
                        acc1[g][1] = MFMA_BF16(a1, b, acc1[g][1]);
                    }
                }
            }
        }

        // ======== FWD layer0(t): acc0 = h0(t-1) @ Whh0^T ========
        f32x4 acc0[4][2];
        if (t < FSTEPS) {
#pragma unroll
            for (int g = 0; g < 4; ++g) { acc0[g][0] = (f32x4){0.f,0.f,0.f,0.f}; acc0[g][1] = (f32x4){0.f,0.f,0.f,0.f}; }
            if (t >= 1) {
#pragma unroll
                for (int kc = 0; kc < 8; ++kc) {
                    bf16x8 a0 = ldsA(T0, (lane & 15),      kc * 32 + klane * 8);
                    bf16x8 a1 = ldsA(T0, 16 + (lane & 15), kc * 32 + klane * 8);
#pragma unroll
                    for (int g = 0; g < 4; ++g) {
                        bf16x8 b = P0vf[(kc * 4 + g) * 64 + lane];
                        acc0[g][0] = MFMA_BF16(a0, b, acc0[g][0]);
                        acc0[g][1] = MFMA_BF16(a1, b, acc0[g][1]);
                    }
                }
            }
        }

        // ---- FWD epilogue0: cell layer0, store h0(t) ----
        if (t < FSTEPS) {
            unsigned* dst = h0g + (size_t)(t & 1) * HPAR32;
#pragma unroll
            for (int Mt = 0; Mt < 2; ++Mt) {
                float hn[4];
#pragma unroll
                for (int r = 0; r < 4; ++r) {
                    float gi = acc0[0][Mt][r] + (float)xqf[Mt][0 * 4 + r];
                    float gf = acc0[1][Mt][r] + (float)xqf[Mt][1 * 4 + r];
                    float gg = acc0[2][Mt][r] + (float)xqf[Mt][2 * 4 + r];
                    float go = acc0[3][Mt][r] + (float)xqf[Mt][3 * 4 + r];
                    float cn = sigm(gf) * c0f[Mt][r] + sigm(gi) * tanh_fast(gg);
                    c0f[Mt][r] = cn;
                    hn[r] = sigm(go) * tanh_fast(cn);
                }
                const int rowbase = rg * 32 + Mt * 16 + q4;
#pragma unroll
                for (int r = 0; r < 4; ++r) {
                    float p = __shfl_xor(hn[r], 1);
                    if (!(lane & 1)) {
                        unsigned w = (unsigned)f2bf(hn[r]) | ((unsigned)f2bf(p) << 16);
                        __hip_atomic_store(dst + (size_t)(rowbase + r) * HROW32 + cp, w,
                                           __ATOMIC_RELAXED, __HIP_MEMORY_SCOPE_AGENT);
                    }
                }
            }
        }

        // ---- FWD epilogue1: cell layer1, store h1(t-1) / latent dir0 ----
        if (t >= 1) {
#pragma unroll
            for (int Mt = 0; Mt < 2; ++Mt) {
                float hn[4];
#pragma unroll
                for (int r = 0; r < 4; ++r) {
                    float gi = acc1[0][Mt][r] + b1f[0];
                    float gf = acc1[1][Mt][r] + b1f[1];
                    float gg = acc1[2][Mt][r] + b1f[2];
                    float go = acc1[3][Mt][r] + b1f[3];
                    float cn = sigm(gf) * c1f[Mt][r] + sigm(gi) * tanh_fast(gg);
                    c1f[Mt][r] = cn;
                    hn[r] = sigm(go) * tanh_fast(cn);
                }
                const int rowbase = rg * 32 + Mt * 16 + q4;
                if (t < FSTEPS) {
                    unsigned* dst = h1g + (size_t)((t - 1) & 1) * HPAR32;
#pragma unroll
                    for (int r = 0; r < 4; ++r) {
                        float p = __shfl_xor(hn[r], 1);
                        if (!(lane & 1)) {
                            unsigned w = (unsigned)f2bf(hn[r]) | ((unsigned)f2bf(p) << 16);
                            __hip_atomic_store(dst + (size_t)(rowbase + r) * HROW32 + cp, w,
                                               __ATOMIC_RELAXED, __HIP_MEMORY_SCOPE_AGENT);
                        }
                    }
                } else {
#pragma unroll
                    for (int r = 0; r < 4; ++r)
                        latent[(size_t)(rowbase + r) * 512 + hc] = hn[r];
                }
            }
        }

        // ======== REV (folded): layer1(t-1) for t=1..3, layer0(t) for t=0..2 ========
        if (t <= 3) {
            // REV layer1(t-1)
            if (t >= 1) {
                f32x4 ar1[4][2];
#pragma unroll
                for (int g = 0; g < 4; ++g) { ar1[g][0] = (f32x4){0.f,0.f,0.f,0.f}; ar1[g][1] = (f32x4){0.f,0.f,0.f,0.f}; }
#pragma unroll
                for (int kc = 0; kc < 8; ++kc) {
                    bf16x8 a0 = ldsA(T0r, (lane & 15),      kc * 32 + klane * 8);
                    bf16x8 a1 = ldsA(T0r, 16 + (lane & 15), kc * 32 + klane * 8);
#pragma unroll
                    for (int g = 0; g < 4; ++g) {
                        bf16x8 b = P1vr[(kc * 4 + g) * 64 + lane];
                        ar1[g][0] = MFMA_BF16(a0, b, ar1[g][0]);
                        ar1[g][1] = MFMA_BF16(a1, b, ar1[g][1]);
                    }
                }
                if (t >= 2) {
#pragma unroll
                    for (int kc = 0; kc < 8; ++kc) {
                        bf16x8 a0 = ldsA(T1r, (lane & 15),      kc * 32 + klane * 8);
                        bf16x8 a1 = ldsA(T1r, 16 + (lane & 15), kc * 32 + klane * 8);
#pragma unroll
                        for (int g = 0; g < 4; ++g) {
                            bf16x8 b = P1vr[((kc + 8) * 4 + g) * 64 + lane];
                            ar1[g][0] = MFMA_BF16(a0, b, ar1[g][0]);
                            ar1[g][1] = MFMA_BF16(a1, b, ar1[g][1]);
                        }
                    }
                }
#pragma unroll
                for (int Mt = 0; Mt < 2; ++Mt) {
                    float hn[4];
#pragma unroll
                    for (int r = 0; r < 4; ++r) {
                        float gi = ar1[0][Mt][r] + b1r[0];
                        float gf = ar1[1][Mt][r] + b1r[1];
                        float gg = ar1[2][Mt][r] + b1r[2];
                        float go = ar1[3][Mt][r] + b1r[3];
                        float cn = sigm(gf) * c1r[Mt][r] + sigm(gi) * tanh_fast(gg);
                        c1r[Mt][r] = cn;
                        hn[r] = sigm(go) * tanh_fast(cn);
                    }
                    const int rowbase = rg * 32 + Mt * 16 + q4;
                    if (t < RSTEPS) {    // t = 1,2 -> store h1r(t-1)
                        unsigned* dst = h1gr + (size_t)((t - 1) & 1) * HPAR32;
#pragma unroll
                        for (int r = 0; r < 4; ++r) {
                            float p = __shfl_xor(hn[r], 1);
                            if (!(lane & 1)) {
                                unsigned w = (unsigned)f2bf(hn[r]) | ((unsigned)f2bf(p) << 16);
                                __hip_atomic_store(dst + (size_t)(rowbase + r) * HROW32 + cp, w,
                                                   __ATOMIC_RELAXED, __HIP_MEMORY_SCOPE_AGENT);
                            }
                        }
                    } else {             // t = 3 -> rev final: latent dir1
#pragma unroll
                        for (int r = 0; r < 4; ++r)
                            latent[(size_t)(rowbase + r) * 512 + 256 + hc] = hn[r];
                    }
                }
            }

            // REV layer0(t) for t=0..2
            if (t < RSTEPS) {
                f32x4 ar0[4][2];
#pragma unroll
                for (int g = 0; g < 4; ++g) { ar0[g][0] = (f32x4){0.f,0.f,0.f,0.f}; ar0[g][1] = (f32x4){0.f,0.f,0.f,0.f}; }
                if (t >= 1) {
#pragma unroll
                    for (int kc = 0; kc < 8; ++kc) {
                        bf16x8 a0 = ldsA(T0r, (lane & 15),      kc * 32 + klane * 8);
                        bf16x8 a1 = ldsA(T0r, 16 + (lane & 15), kc * 32 + klane * 8);
#pragma unroll
                        for (int g = 0; g < 4; ++g) {
                            bf16x8 b = P0vr[(kc * 4 + g) * 64 + lane];
                            ar0[g][0] = MFMA_BF16(a0, b, ar0[g][0]);
                            ar0[g][1] = MFMA_BF16(a1, b, ar0[g][1]);
                        }
                    }
                }
                unsigned* dst = h0gr + (size_t)(t & 1) * HPAR32;
#pragma unroll
                for (int Mt = 0; Mt < 2; ++Mt) {
                    float hn[4];
#pragma unroll
                    for (int r = 0; r < 4; ++r) {
                        float gi = ar0[0][Mt][r] + (float)xqr[Mt][0 * 4 + r];
                        float gf = ar0[1][Mt][r] + (float)xqr[Mt][1 * 4 + r];
                        float gg = ar0[2][Mt][r] + (float)xqr[Mt][2 * 4 + r];
                        float go = ar0[3][Mt][r] + (float)xqr[Mt][3 * 4 + r];
                        float cn = sigm(gf) * c0r[Mt][r] + sigm(gi) * tanh_fast(gg);
                        c0r[Mt][r] = cn;
                        hn[r] = sigm(go) * tanh_fast(cn);
                    }
                    const int rowbase = rg * 32 + Mt * 16 + q4;
#pragma unroll
                    for (int r = 0; r < 4; ++r) {
                        float p = __shfl_xor(hn[r], 1);
                        if (!(lane & 1)) {
                            unsigned w = (unsigned)f2bf(hn[r]) | ((unsigned)f2bf(p) << 16);
                            __hip_atomic_store(dst + (size_t)(rowbase + r) * HROW32 + cp, w,
                                               __ATOMIC_RELAXED, __HIP_MEMORY_SCOPE_AGENT);
                        }
                    }
                }
            }
        }

        // ---- 4-way barrier: 1 RMW + hot poll; prefetch xq; reload tiles ----
        if (t < FSTEPS) {
            ++bcount;
            asm volatile("s_waitcnt vmcnt(0)" ::: "memory");  // drain this wave's sc1 stores
            __syncthreads();
            if (tid == 0)
                __hip_atomic_fetch_add(flag, 1u, __ATOMIC_RELAXED, __HIP_MEMORY_SCOPE_AGENT);
            // prefetch next step's xq while waiting
            if (t + 1 < FSTEPS) {
#pragma unroll
                for (int Mt = 0; Mt < 2; ++Mt)
                    xqf[Mt] = *(const f16x16*)(xp +
                        ((((size_t)(t + 1) * 128 + rg * 2 + Mt) * 16 + mem) * 64 + lane) * 16);
            }
            if (t + 1 < RSTEPS) {
#pragma unroll
                for (int Mt = 0; Mt < 2; ++Mt)
                    xqr[Mt] = *(const f16x16*)(xp +
                        ((((size_t)(32 + t + 1) * 128 + rg * 2 + Mt) * 16 + mem) * 64 + lane) * 16);
            }
            if (tid == 0) {
                while (__hip_atomic_load(flag, __ATOMIC_RELAXED, __HIP_MEMORY_SCOPE_AGENT)
                       < 4u * bcount) {}
            }
            __syncthreads();
            __builtin_amdgcn_sched_barrier(0);
            reload32(T0, (const u64*)(h0g + (size_t)(t & 1) * HPAR32), rg, tid);
            if (t >= 1)
                reload32(T1, (const u64*)(h1g + (size_t)((t - 1) & 1) * HPAR32), rg, tid);
            if (t < RSTEPS)          // t=0,1,2: rev h0(t) consumed at t+1
                reload32(T0r, (const u64*)(h0gr + (size_t)(t & 1) * HPAR32), rg, tid);
            if (t >= 1 && t < RSTEPS)  // t=1,2: rev h1(t-1) consumed at t+1
                reload32(T1r, (const u64*)(h1gr + (size_t)((t - 1) & 1) * HPAR32), rg, tid);
            __syncthreads();
        }
    }
}

// ---------------- x-projection GEMM (r14: u64-packed epilogue, proven) ----------------
__global__ void __launch_bounds__(256)
xproj_gemm(const float* __restrict__ xs,
           const u16* __restrict__ W0xf, const u16* __restrict__ W0xr,
           const float* __restrict__ bs0f, const float* __restrict__ bs0r,
           _Float16* __restrict__ xp)
{
    __shared__ char As[16384];
    __shared__ char Bs[16384];
    const int tid = threadIdx.x, wv = tid >> 6, lane = tid & 63;
    const int phys = blockIdx.x;
    const int xcd = phys & 7, idx = phys >> 3;
    const int mt = xcd * 70 + (idx >> 3);     // 0..559
    const int nt = idx & 7;
    const int vf = mt >> 4;
    const int dirr = (vf >= 32);
    const int frame = dirr ? (95 - vf) : (30 + vf);
    const int brow = (mt & 15) * 128;
    const u16* Wp = (dirr ? W0xr : W0xf) + (size_t)nt * 128 * 512;
    const float* bs = dirr ? bs0r : bs0f;

    float breg[8];
#pragma unroll
    for (int n = 0; n < 8; ++n) breg[n] = bs[nt * 128 + n * 16 + (lane & 15)];

    f32x4 acc[8][2];
#pragma unroll
    for (int n = 0; n < 8; ++n) { acc[n][0] = (f32x4){0.f,0.f,0.f,0.f}; acc[n][1] = (f32x4){0.f,0.f,0.f,0.f}; }

    const int ar = tid >> 1, akoff = (tid & 1) * 32;
    const float* asrc0 = xs + ((size_t)(brow + ar) * 64 + frame) * 512 + akoff;

    for (int c = 0; c < 8; ++c) {
        {   // stage A: 128 rows x 64 k, fp32 -> bf16
            const float* s = asrc0 + c * 64;
            u16x8 o[4];
#pragma unroll
            for (int j2 = 0; j2 < 4; ++j2) {
                float4 f0 = *(const float4*)(s + j2 * 8);
                float4 f1 = *(const float4*)(s + j2 * 8 + 4);
                u16x8 o_;
                o_[0] = f2bf(f0.x); o_[1] = f2bf(f0.y); o_[2] = f2bf(f0.z); o_[3] = f2bf(f0.w);
                o_[4] = f2bf(f1.x); o_[5] = f2bf(f1.y); o_[6] = f2bf(f1.z); o_[7] = f2bf(f1.w);
                o[j2] = o_;
            }
#pragma unroll
            for (int j2 = 0; j2 < 4; ++j2) {
                int k = akoff + j2 * 8;
                int byte = (ar << 7) + (k << 1); byte ^= (ar & 7) << 4;
                *(u16x8*)(As + byte) = o[j2];
            }
        }
#pragma unroll
        for (int i = 0; i < 4; ++i) {   // stage B: 128 rows x 64 k
            int u = tid + i * 256;
            int ns = u >> 3, c8 = (u & 7) << 3;
            u16x8 v = *(const u16x8*)(Wp + (size_t)ns * 512 + c * 64 + c8);
            int byte = (ns << 7) + (c8 << 1); byte ^= (ns & 7) << 4;
            *(u16x8*)(Bs + byte) = v;
        }
        __syncthreads();
#pragma unroll
        for (int kk = 0; kk < 2; ++kk) {
            int kin = kk * 32 + (lane >> 4) * 8;
            bf16x8 a0, a1;
            int row = wv * 32 + (lane & 15);
            int byte = (row << 7) + (kin << 1); byte ^= (row & 7) << 4;
            a0 = *(const bf16x8*)(As + byte);
            int row1 = row + 16;
            byte = (row1 << 7) + (kin << 1); byte ^= (row1 & 7) << 4;
            a1 = *(const bf16x8*)(As + byte);
#pragma unroll
            for (int n = 0; n < 8; ++n) {
                int ns = n * 16 + (lane & 15);
                int bb = (ns << 7) + (kin << 1); bb ^= (ns & 7) << 4;
                bf16x8 bf_ = *(const bf16x8*)(Bs + bb);
                acc[n][0] = MFMA_BF16(a0, bf_, acc[n][0]);
                acc[n][1] = MFMA_BF16(a1, bf_, acc[n][1]);
            }
        }
        __syncthreads();
    }
    // epilogue: gather layout [vf][rb128][m16][lane64][16]; 4 r-values contiguous -> u64 store
#pragma unroll
    for (int n = 0; n < 8; ++n)
#pragma unroll
        for (int mm = 0; mm < 2; ++mm) {
            u64 pk = 0;
#pragma unroll
            for (int r = 0; r < 4; ++r)
                pk |= (u64)f2h(acc[n][mm][r] + breg[n]) << (16 * r);
            int vm  = mt * 128 + wv * 32 + mm * 16 + ((lane >> 4) << 2);   // r = 0 base
            int col = nt * 128 + n * 16 + (lane & 15);
            int vf2 = vm >> 11, brow2 = vm & 2047;
            int rb2 = brow2 >> 4, sub = brow2 & 15;
            int lane2 = ((sub >> 2) << 4) + (col & 15);
            int m2 = (col >> 4) & 15, g2 = col >> 8;
            size_t o = ((((size_t)vf2 * 128 + rb2) * 16 + m2) * 64 + lane2) * 16 + (g2 << 2);
            *(u64*)(xp + o) = pk;
        }
}

// ---------------- prep kernels (r10-proven) ----------------
__global__ void pack_w(const float* __restrict__ Wa, int da,
                       const float* __restrict__ bi, const float* __restrict__ bh,
                       u16* __restrict__ Wout, float* __restrict__ bout)
{
    int total = 1024 * da;
    int gt = blockIdx.x * blockDim.x + threadIdx.x;
    int stride = gridDim.x * blockDim.x;
    for (int i = gt; i < total; i += stride) Wout[i] = f2bf(Wa[i]);
    if (bout && gt < 1024) bout[gt] = bi[gt] + bh[gt];
}

// fragment-ordered pack: u -> l=u&63, g=(u>>6)&3, t2=u>>8, kc=t2%nkc, mem=t2/nkc;
// row = g*256 + mem*16 + (l&15); k0 = kc*32 + (l>>4)*8
__global__ void pack_frag(const float* __restrict__ Wa, int da,
                          const float* __restrict__ Wb, int db,
                          int nkc, u16* __restrict__ out,
                          const float* __restrict__ bi, const float* __restrict__ bh,
                          float* __restrict__ bout)
{
    int total = 16 * nkc * 4 * 64;
    int gt = blockIdx.x * blockDim.x + threadIdx.x;
    int stride = gridDim.x * blockDim.x;
    for (int u = gt; u < total; u += stride) {
        int l = u & 63;
        int t1 = u >> 6;
        int g = t1 & 3;
        int t2 = t1 >> 2;
        int kc = t2 % nkc;
        int mem = t2 / nkc;
        int row = g * 256 + mem * 16 + (l & 15);
        int k0 = kc * 32 + ((l >> 4) << 3);
        u16x8 o;
#pragma unroll
        for (int jj = 0; jj < 8; ++jj) {
            int k = k0 + jj;
            float v = (k < da) ? Wa[(size_t)row * da + k] : Wb[(size_t)row * db + (k - da)];
            o[jj] = f2bf(v);
        }
        *(u16x8*)(out + (size_t)u * 8) = o;
    }
    if (bout && gt < 1024) bout[gt] = bi[gt] + bh[gt];
}

// ---------------- final linear ----------------
__global__ void final_linear(const float* __restrict__ latent, const float* __restrict__ W3,
                             const float* __restrict__ b3, float* __restrict__ out)
{
    int idx = blockIdx.x * blockDim.x + threadIdx.x;
    if (idx >= BATCH * 10) return;
    int bb = idx / 10, c = idx - bb * 10;
    const float* lrow = latent + (size_t)bb * 512;
    const float* wrow = W3 + (size_t)c * 512;
    float s = b3[c];
#pragma unroll 4
    for (int k = 0; k < 512; k += 4) {
        float4 lv = *(const float4*)(lrow + k);
        float4 wv = *(const float4*)(wrow + k);
        s += lv.x * wv.x + lv.y * wv.y + lv.z * wv.z + lv.w * wv.w;
    }
    out[idx] = s;
}

// ---------------- launch ----------------
extern "C" void kernel_launch(void* const* d_in, const int* in_sizes, int n_in,
                              void* d_out, int out_size, void* d_ws, size_t ws_size,
                              hipStream_t stream)
{
    (void)in_sizes; (void)n_in; (void)out_size;
    if (ws_size < WS_NEED) return;   // leaves d_out poisoned -> diagnosable as ws shortfall

    const float* xs     = (const float*)d_in[0];
    const float* Wih_f0 = (const float*)d_in[1];
    const float* Whh_f0 = (const float*)d_in[2];
    const float* bih_f0 = (const float*)d_in[3];
    const float* bhh_f0 = (const float*)d_in[4];
    const float* Wih_f1 = (const float*)d_in[5];
    const float* Whh_f1 = (const float*)d_in[6];
    const float* bih_f1 = (const float*)d_in[7];
    const float* bhh_f1 = (const float*)d_in[8];
    const float* Wih_r0 = (const float*)d_in[9];
    const float* Whh_r0 = (const float*)d_in[10];
    const float* bih_r0 = (const float*)d_in[11];
    const float* bhh_r0 = (const float*)d_in[12];
    const float* Wih_r1 = (const float*)d_in[13];
    const float* Whh_r1 = (const float*)d_in[14];
    const float* bih_r1 = (const float*)d_in[15];
    const float* bhh_r1 = (const float*)d_in[16];
    const float* W3     = (const float*)d_in[17];
    const float* b3     = (const float*)d_in[18];

    char* ws = (char*)d_ws;
    unsigned* ctl  = (unsigned*)(ws + OFF_CTL);
    unsigned* h0g  = (unsigned*)(ws + OFF_H0G);
    unsigned* h1g  = (unsigned*)(ws + OFF_H1G);
    unsigned* h0gr = (unsigned*)(ws + OFF_H0GR);
    unsigned* h1gr = (unsigned*)(ws + OFF_H1GR);
    float* latent = (float*)(ws + OFF_LAT);
    _Float16* xp  = (_Float16*)(ws + OFF_XP);
    u16* W0xf = (u16*)(ws + OFF_W0XF);
    u16* W0xr = (u16*)(ws + OFF_W0XR);
    u16* P0f  = (u16*)(ws + OFF_P0F);
    u16* P0r  = (u16*)(ws + OFF_P0R);
    u16* P1f  = (u16*)(ws + OFF_P1F);
    u16* P1r  = (u16*)(ws + OFF_P1R);
    float* bs0f = (float*)(ws + OFF_BS0F);
    float* bs0r = (float*)(ws + OFF_BS0R);
    float* bs1f = (float*)(ws + OFF_BS1F);
    float* bs1r = (float*)(ws + OFF_BS1R);

    hipMemsetAsync(ctl, 0, 32768, stream);   // flag lines only

    pack_w<<<256, 256, 0, stream>>>(Wih_f0, 512, bih_f0, bhh_f0, W0xf, bs0f);
    pack_w<<<256, 256, 0, stream>>>(Wih_r0, 512, bih_r0, bhh_r0, W0xr, bs0r);
    pack_frag<<<64, 256, 0, stream>>>(Whh_f0, 256, Whh_f0, 0, 8,  P0f, nullptr, nullptr, nullptr);
    pack_frag<<<64, 256, 0, stream>>>(Whh_r0, 256, Whh_r0, 0, 8,  P0r, nullptr, nullptr, nullptr);
    pack_frag<<<64, 256, 0, stream>>>(Wih_f1, 256, Whh_f1, 256, 16, P1f, bih_f1, bhh_f1, bs1f);
    pack_frag<<<64, 256, 0, stream>>>(Wih_r1, 256, Whh_r1, 256, 16, P1r, bih_r1, bhh_r1, bs1r);

    xproj_gemm<<<4480, 256, 0, stream>>>(xs, W0xf, W0xr, bs0f, bs0r, xp);

    lstm_seq<<<256, 256, 0, stream>>>(xp, P0f, P0r, P1f, P1r, bs1f, bs1r,
                                      h0g, h1g, h0gr, h1gr, latent, ctl);

    final_linear<<<80, 256, 0, stream>>>(latent, W3, b3, (float*)d_out);
}

// Round 16
// 866.927 us; speedup vs baseline: 1.0926x; 1.0926x over previous
//
#include <hip/hip_runtime.h>
#include <stdint.h>

// ---------------- types ----------------
typedef unsigned short u16;
typedef unsigned long long u64;
typedef __attribute__((ext_vector_type(8)))  short  bf16x8;   // 8 bf16 (MFMA A/B frag)
typedef __attribute__((ext_vector_type(8)))  u16    u16x8;
typedef __attribute__((ext_vector_type(4)))  float  f32x4;
typedef __attribute__((ext_vector_type(16))) _Float16 f16x16; // 32B chunk

#define MFMA_BF16(a,b,c) __builtin_amdgcn_mfma_f32_16x16x32_bf16((a),(b),(c),0,0,0)

// ---------------- problem constants ----------------
#define BATCH   2048
#define FSTEPS  32
#define RSTEPS  3
#define NVF     35            // 32 fwd virtual frames + 3 rev (63,62,61)

// h global buffers: [parity][2048 rows][128 u32] (256 bf16 cols packed in pairs)
static constexpr size_t HROW32 = 128;
static constexpr size_t HPAR32 = (size_t)BATCH * HROW32;

// ---------------- ws layout (bytes) ----------------
static constexpr size_t OFF_CTL  = 0;                                  // 32 KB flag lines (zeroed)
static constexpr size_t OFF_H0G  = 32768;                              // 2 MiB (2 parities)
static constexpr size_t OFF_H1G  = OFF_H0G + HPAR32 * 2 * 4;
static constexpr size_t OFF_LAT  = OFF_H1G + HPAR32 * 2 * 4;           // latent fp32 (2048x512)
static constexpr size_t OFF_XP   = OFF_LAT + (size_t)BATCH * 512 * 4;  // xproj fp16 gather layout
static constexpr size_t XP_BYTES = (size_t)NVF * BATCH * 1024 * 2;     // [vf][rb128][m16][lane64][16]
static constexpr size_t OFF_W0XF = OFF_XP + XP_BYTES;                  // Wih0 row-major bf16 [1024][512]
static constexpr size_t OFF_W0XR = OFF_W0XF + (size_t)1024 * 512 * 2;
static constexpr size_t OFF_P0F  = OFF_W0XR + (size_t)1024 * 512 * 2;  // Whh0 frag-packed 512 KB
static constexpr size_t OFF_P0R  = OFF_P0F + (size_t)32768 * 16;
static constexpr size_t OFF_P1F  = OFF_P0R + (size_t)32768 * 16;       // W1 frag-packed 1 MB
static constexpr size_t OFF_P1R  = OFF_P1F + (size_t)65536 * 16;
static constexpr size_t OFF_BS0F = OFF_P1R + (size_t)65536 * 16;       // bias sums fp32 [1024]
static constexpr size_t OFF_BS0R = OFF_BS0F + 4096;
static constexpr size_t OFF_BS1F = OFF_BS0R + 4096;
static constexpr size_t OFF_BS1R = OFF_BS1F + 4096;
static constexpr size_t WS_NEED  = OFF_BS1R + 4096;                    // ~157 MB (r10-proven)

// ---------------- small helpers ----------------
__device__ __forceinline__ u16 f2bf(float f) {
    unsigned u = __float_as_uint(f);
    unsigned r = (u + 0x7fffu + ((u >> 16) & 1u)) >> 16;
    return (u16)r;
}
__device__ __forceinline__ float sigm(float x) { return 1.0f / (1.0f + __expf(-x)); }
__device__ __forceinline__ float tanh_fast(float x) {
    float a = fabsf(x);
    float e = __expf(-2.0f * a);
    float t = (1.0f - e) / (1.0f + e);
    return x < 0.0f ? -t : t;
}
__device__ __forceinline__ u16 f2h(float f) {   // fp32 -> fp16 bits
    _Float16 h = (_Float16)f;
    union { _Float16 h; u16 b; } u; u.h = h; return u.b;
}

// LDS h tile: [32 rows][256 bf16], row stride 512B, XOR swizzle on byte bits 4-6
__device__ __forceinline__ bf16x8 ldsA(const char* H, int row, int k) {
    int byte = (row << 9) + (k << 1);
    byte ^= (row & 7) << 4;
    return *(const bf16x8*)(H + byte);
}

// reload 32x256 h tile (16KB) from global parity buffer into LDS (sc1 u64 loads)
__device__ __forceinline__ void reload32(char* Hs, const u64* src, int rg, int tid) {
    u64 v[8];
#pragma unroll
    for (int i = 0; i < 8; ++i) {
        int idx = tid + (i << 8);                 // 0..2047
        v[i] = __hip_atomic_load(src + ((size_t)rg * 32 + (idx >> 6)) * 64 + (idx & 63),
                                 __ATOMIC_RELAXED, __HIP_MEMORY_SCOPE_AGENT);
    }
#pragma unroll
    for (int i = 0; i < 8; ++i) {
        int idx = tid + (i << 8);
        int row = idx >> 6, cu = idx & 63;
        int byte = (row << 9) + (cu << 3);
        byte ^= (row & 7) << 4;
        *(u64*)(Hs + byte) = v[i];
    }
}

// ---------------- persistent sequential kernel (r10 verbatim, 619 us proven) ----------------
// 256 blocks x 256 thr (4 waves), 1 block/CU. Block = M=32 rows x 256 gate-cols.
// Decode: colq = bid>>6 (0..3), rg = bid&63. Partners {rg, rg+64, rg+128, rg+192}
// share bid%8 -> same XCD under round-robin dispatch (perf heuristic only).
// Wave wq owns 64 gate-cols -> weight slice mem = colq*4+wq (96 KB/wave from L2,
// 384 KB/CU/step -> L2-resident; per-XCD unique set 1.5 MB). Merged phase
// (layer1(t-1)+layer0(t)), ONE 4-way barrier/step: single monotonic RMW flag,
// hot poll, xq prefetched across the barrier. h staged into LDS once per block.
__global__ void __launch_bounds__(256)
lstm_seq(const _Float16* __restrict__ xp,
         const u16* __restrict__ P0f_, const u16* __restrict__ P0r_,
         const u16* __restrict__ P1f_, const u16* __restrict__ P1r_,
         const float* __restrict__ bs1f, const float* __restrict__ bs1r,
         unsigned* __restrict__ h0g, unsigned* __restrict__ h1g,
         float* __restrict__ latent, unsigned* __restrict__ ctl)
{
    __shared__ char T0[16384];   // h0 tile: 32 rows x 256 bf16, swizzled
    __shared__ char T1[16384];   // h1 tile
    const int tid = threadIdx.x, wq = tid >> 6, lane = tid & 63;
    const int bid = blockIdx.x;
    const int colq = bid >> 6;                 // 0..3
    const int rg   = bid & 63;                 // 0..63
    const int mem  = colq * 4 + wq;            // 0..15 (weight slice / h-col-16-block)
    const int hc   = mem * 16 + (lane & 15);
    const int klane = lane >> 4, q4 = klane << 2;
    unsigned* flag = ctl + (size_t)rg * 64;    // 256B line per group
    unsigned bcount = 0;

    for (int dir = 0; dir < 2; ++dir) {
        const int nst = dir ? RSTEPS : FSTEPS;
        const int gbase = dir ? FSTEPS : 0;
        const bf16x8* P0v = (const bf16x8*)(dir ? P0r_ : P0f_) + (size_t)mem * (8 * 4 * 64);
        const bf16x8* P1v = (const bf16x8*)(dir ? P1r_ : P1f_) + (size_t)mem * (16 * 4 * 64);
        const float* bs1 = dir ? bs1r : bs1f;
        float b1reg[4];
#pragma unroll
        for (int g = 0; g < 4; ++g) b1reg[g] = bs1[g * 256 + hc];

        float c0[2][4], c1[2][4];
#pragma unroll
        for (int Mt = 0; Mt < 2; ++Mt)
#pragma unroll
            for (int r = 0; r < 4; ++r) { c0[Mt][r] = 0.f; c1[Mt][r] = 0.f; }

        // zero both tiles (h0(-1) = h1(-1) = 0)
        __syncthreads();
#pragma unroll
        for (int i = 0; i < 4; ++i) {
            ((f32x4*)T0)[i * 256 + tid] = (f32x4){0.f, 0.f, 0.f, 0.f};
            ((f32x4*)T1)[i * 256 + tid] = (f32x4){0.f, 0.f, 0.f, 0.f};
        }
        __syncthreads();

        // xq for t=0 (per Mt: 32B contiguous per lane)
        f16x16 xqm[2];
#pragma unroll
        for (int Mt = 0; Mt < 2; ++Mt)
            xqm[Mt] = *(const f16x16*)(xp +
                ((((size_t)gbase * 128 + rg * 2 + Mt) * 16 + mem) * 64 + lane) * 16);

        for (int t = 0; t <= nst; ++t) {
            // ======== layer1(t-1): acc1 = [h0(t-1) | h1(t-2)] @ W1^T ========
            f32x4 acc1[4][2];
            if (t >= 1) {
#pragma unroll
                for (int g = 0; g < 4; ++g) { acc1[g][0] = (f32x4){0.f,0.f,0.f,0.f}; acc1[g][1] = (f32x4){0.f,0.f,0.f,0.f}; }
#pragma unroll
                for (int kc = 0; kc < 8; ++kc) {
                    bf16x8 a0 = ldsA(T0, (lane & 15),       kc * 32 + klane * 8);
                    bf16x8 a1 = ldsA(T0, 16 + (lane & 15),  kc * 32 + klane * 8);
#pragma unroll
                    for (int g = 0; g < 4; ++g) {
                        bf16x8 b = P1v[(kc * 4 + g) * 64 + lane];
                        acc1[g][0] = MFMA_BF16(a0, b, acc1[g][0]);
                        acc1[g][1] = MFMA_BF16(a1, b, acc1[g][1]);
                    }
                }
                if (t >= 2) {
#pragma unroll
                    for (int kc = 0; kc < 8; ++kc) {
                        bf16x8 a0 = ldsA(T1, (lane & 15),      kc * 32 + klane * 8);
                        bf16x8 a1 = ldsA(T1, 16 + (lane & 15), kc * 32 + klane * 8);
#pragma unroll
                        for (int g = 0; g < 4; ++g) {
                            bf16x8 b = P1v[((kc + 8) * 4 + g) * 64 + lane];
                            acc1[g][0] = MFMA_BF16(a0, b, acc1[g][0]);
                            acc1[g][1] = MFMA_BF16(a1, b, acc1[g][1]);
                        }
                    }
                }
            }

            // ======== layer0(t): acc0 = h0(t-1) @ Whh0^T ========
            f32x4 acc0[4][2];
            if (t < nst) {
#pragma unroll
                for (int g = 0; g < 4; ++g) { acc0[g][0] = (f32x4){0.f,0.f,0.f,0.f}; acc0[g][1] = (f32x4){0.f,0.f,0.f,0.f}; }
                if (t >= 1) {
#pragma unroll
                    for (int kc = 0; kc < 8; ++kc) {
                        bf16x8 a0 = ldsA(T0, (lane & 15),      kc * 32 + klane * 8);
                        bf16x8 a1 = ldsA(T0, 16 + (lane & 15), kc * 32 + klane * 8);
#pragma unroll
                        for (int g = 0; g < 4; ++g) {
                            bf16x8 b = P0v[(kc * 4 + g) * 64 + lane];
                            acc0[g][0] = MFMA_BF16(a0, b, acc0[g][0]);
                            acc0[g][1] = MFMA_BF16(a1, b, acc0[g][1]);
                        }
                    }
                }
            }

            // ---- epilogue0: cell layer0, store h0(t) (sc1, packed u32) ----
            if (t < nst) {
                unsigned* dst = h0g + (size_t)(t & 1) * HPAR32;
                const int cp = mem * 8 + ((lane & 15) >> 1);
#pragma unroll
                for (int Mt = 0; Mt < 2; ++Mt) {
                    float hn[4];
#pragma unroll
                    for (int r = 0; r < 4; ++r) {
                        float gi = acc0[0][Mt][r] + (float)xqm[Mt][0 * 4 + r];
                        float gf = acc0[1][Mt][r] + (float)xqm[Mt][1 * 4 + r];
                        float gg = acc0[2][Mt][r] + (float)xqm[Mt][2 * 4 + r];
                        float go = acc0[3][Mt][r] + (float)xqm[Mt][3 * 4 + r];
                        float cn = sigm(gf) * c0[Mt][r] + sigm(gi) * tanh_fast(gg);
                        c0[Mt][r] = cn;
                        hn[r] = sigm(go) * tanh_fast(cn);
                    }
                    const int rowbase = rg * 32 + Mt * 16 + q4;
#pragma unroll
                    for (int r = 0; r < 4; ++r) {
                        float p = __shfl_xor(hn[r], 1);
                        if (!(lane & 1)) {
                            unsigned w = (unsigned)f2bf(hn[r]) | ((unsigned)f2bf(p) << 16);
                            __hip_atomic_store(dst + (size_t)(rowbase + r) * HROW32 + cp, w,
                                               __ATOMIC_RELAXED, __HIP_MEMORY_SCOPE_AGENT);
                        }
                    }
                }
            }

            // ---- epilogue1: cell layer1, store h1(t-1) / latent ----
            if (t >= 1) {
                const int cp = mem * 8 + ((lane & 15) >> 1);
#pragma unroll
                for (int Mt = 0; Mt < 2; ++Mt) {
                    float hn[4];
#pragma unroll
                    for (int r = 0; r < 4; ++r) {
                        float gi = acc1[0][Mt][r] + b1reg[0];
                        float gf = acc1[1][Mt][r] + b1reg[1];
                        float gg = acc1[2][Mt][r] + b1reg[2];
                        float go = acc1[3][Mt][r] + b1reg[3];
                        float cn = sigm(gf) * c1[Mt][r] + sigm(gi) * tanh_fast(gg);
                        c1[Mt][r] = cn;
                        hn[r] = sigm(go) * tanh_fast(cn);
                    }
                    const int rowbase = rg * 32 + Mt * 16 + q4;
                    if (t < nst) {
                        unsigned* dst = h1g + (size_t)((t - 1) & 1) * HPAR32;
#pragma unroll
                        for (int r = 0; r < 4; ++r) {
                            float p = __shfl_xor(hn[r], 1);
                            if (!(lane & 1)) {
                                unsigned w = (unsigned)f2bf(hn[r]) | ((unsigned)f2bf(p) << 16);
                                __hip_atomic_store(dst + (size_t)(rowbase + r) * HROW32 + cp, w,
                                                   __ATOMIC_RELAXED, __HIP_MEMORY_SCOPE_AGENT);
                            }
                        }
                    } else {
#pragma unroll
                        for (int r = 0; r < 4; ++r)
                            latent[(size_t)(rowbase + r) * 512 + dir * 256 + hc] = hn[r];
                    }
                }
            }

            // ---- 4-way barrier: 1 RMW + hot poll; prefetch xq; reload tiles ----
            if (t < nst) {
                ++bcount;
                asm volatile("s_waitcnt vmcnt(0)" ::: "memory");  // drain this wave's sc1 stores
                __syncthreads();
                if (tid == 0)
                    __hip_atomic_fetch_add(flag, 1u, __ATOMIC_RELAXED, __HIP_MEMORY_SCOPE_AGENT);
                // prefetch next step's xq while waiting
                if (t + 1 < nst) {
#pragma unroll
                    for (int Mt = 0; Mt < 2; ++Mt)
                        xqm[Mt] = *(const f16x16*)(xp +
                            ((((size_t)(gbase + t + 1) * 128 + rg * 2 + Mt) * 16 + mem) * 64 + lane) * 16);
                }
                if (tid == 0) {
                    while (__hip_atomic_load(flag, __ATOMIC_RELAXED, __HIP_MEMORY_SCOPE_AGENT)
                           < 4u * bcount) {}
                }
                __syncthreads();
                __builtin_amdgcn_sched_barrier(0);
                reload32(T0, (const u64*)(h0g + (size_t)(t & 1) * HPAR32), rg, tid);
                if (t >= 1)
                    reload32(T1, (const u64*)(h1g + (size_t)((t - 1) & 1) * HPAR32), rg, tid);
                __syncthreads();
            }
        }
    }
}

// ---------------- x-projection GEMM (r14: u64-packed epilogue, proven) ----------------
__global__ void __launch_bounds__(256)
xproj_gemm(const float* __restrict__ xs,
           const u16* __restrict__ W0xf, const u16* __restrict__ W0xr,
           const float* __restrict__ bs0f, const float* __restrict__ bs0r,
           _Float16* __restrict__ xp)
{
    __shared__ char As[16384];
    __shared__ char Bs[16384];
    const int tid = threadIdx.x, wv = tid >> 6, lane = tid & 63;
    const int phys = blockIdx.x;
    const int xcd = phys & 7, idx = phys >> 3;
    const int mt = xcd * 70 + (idx >> 3);     // 0..559
    const int nt = idx & 7;
    const int vf = mt >> 4;
    const int dirr = (vf >= 32);
    const int frame = dirr ? (95 - vf) : (30 + vf);
    const int brow = (mt & 15) * 128;
    const u16* Wp = (dirr ? W0xr : W0xf) + (size_t)nt * 128 * 512;
    const float* bs = dirr ? bs0r : bs0f;

    float breg[8];
#pragma unroll
    for (int n = 0; n < 8; ++n) breg[n] = bs[nt * 128 + n * 16 + (lane & 15)];

    f32x4 acc[8][2];
#pragma unroll
    for (int n = 0; n < 8; ++n) { acc[n][0] = (f32x4){0.f,0.f,0.f,0.f}; acc[n][1] = (f32x4){0.f,0.f,0.f,0.f}; }

    const int ar = tid >> 1, akoff = (tid & 1) * 32;
    const float* asrc0 = xs + ((size_t)(brow + ar) * 64 + frame) * 512 + akoff;

    for (int c = 0; c < 8; ++c) {
        {   // stage A: 128 rows x 64 k, fp32 -> bf16
            const float* s = asrc0 + c * 64;
            u16x8 o[4];
#pragma unroll
            for (int j2 = 0; j2 < 4; ++j2) {
                float4 f0 = *(const float4*)(s + j2 * 8);
                float4 f1 = *(const float4*)(s + j2 * 8 + 4);
                u16x8 o_;
                o_[0] = f2bf(f0.x); o_[1] = f2bf(f0.y); o_[2] = f2bf(f0.z); o_[3] = f2bf(f0.w);
                o_[4] = f2bf(f1.x); o_[5] = f2bf(f1.y); o_[6] = f2bf(f1.z); o_[7] = f2bf(f1.w);
                o[j2] = o_;
            }
#pragma unroll
            for (int j2 = 0; j2 < 4; ++j2) {
                int k = akoff + j2 * 8;
                int byte = (ar << 7) + (k << 1); byte ^= (ar & 7) << 4;
                *(u16x8*)(As + byte) = o[j2];
            }
        }
#pragma unroll
        for (int i = 0; i < 4; ++i) {   // stage B: 128 rows x 64 k
            int u = tid + i * 256;
            int ns = u >> 3, c8 = (u & 7) << 3;
            u16x8 v = *(const u16x8*)(Wp + (size_t)ns * 512 + c * 64 + c8);
            int byte = (ns << 7) + (c8 << 1); byte ^= (ns & 7) << 4;
            *(u16x8*)(Bs + byte) = v;
        }
        __syncthreads();
#pragma unroll
        for (int kk = 0; kk < 2; ++kk) {
            int kin = kk * 32 + (lane >> 4) * 8;
            bf16x8 a0, a1;
            int row = wv * 32 + (lane & 15);
            int byte = (row << 7) + (kin << 1); byte ^= (row & 7) << 4;
            a0 = *(const bf16x8*)(As + byte);
            int row1 = row + 16;
            byte = (row1 << 7) + (kin << 1); byte ^= (row1 & 7) << 4;
            a1 = *(const bf16x8*)(As + byte);
#pragma unroll
            for (int n = 0; n < 8; ++n) {
                int ns = n * 16 + (lane & 15);
                int bb = (ns << 7) + (kin << 1); bb ^= (ns & 7) << 4;
                bf16x8 bf_ = *(const bf16x8*)(Bs + bb);
                acc[n][0] = MFMA_BF16(a0, bf_, acc[n][0]);
                acc[n][1] = MFMA_BF16(a1, bf_, acc[n][1]);
            }
        }
        __syncthreads();
    }
    // epilogue: gather layout [vf][rb128][m16][lane64][16]; 4 r-values contiguous -> u64 store
#pragma unroll
    for (int n = 0; n < 8; ++n)
#pragma unroll
        for (int mm = 0; mm < 2; ++mm) {
            u64 pk = 0;
#pragma unroll
            for (int r = 0; r < 4; ++r)
                pk |= (u64)f2h(acc[n][mm][r] + breg[n]) << (16 * r);
            int vm  = mt * 128 + wv * 32 + mm * 16 + ((lane >> 4) << 2);   // r = 0 base
            int col = nt * 128 + n * 16 + (lane & 15);
            int vf2 = vm >> 11, brow2 = vm & 2047;
            int rb2 = brow2 >> 4, sub = brow2 & 15;
            int lane2 = ((sub >> 2) << 4) + (col & 15);
            int m2 = (col >> 4) & 15, g2 = col >> 8;
            size_t o = ((((size_t)vf2 * 128 + rb2) * 16 + m2) * 64 + lane2) * 16 + (g2 << 2);
            *(u64*)(xp + o) = pk;
        }
}

// ---------------- prep kernels (r10-proven) ----------------
__global__ void pack_w(const float* __restrict__ Wa, int da,
                       const float* __restrict__ bi, const float* __restrict__ bh,
                       u16* __restrict__ Wout, float* __restrict__ bout)
{
    int total = 1024 * da;
    int gt = blockIdx.x * blockDim.x + threadIdx.x;
    int stride = gridDim.x * blockDim.x;
    for (int i = gt; i < total; i += stride) Wout[i] = f2bf(Wa[i]);
    if (bout && gt < 1024) bout[gt] = bi[gt] + bh[gt];
}

// fragment-ordered pack: u -> l=u&63, g=(u>>6)&3, t2=u>>8, kc=t2%nkc, mem=t2/nkc;
// row = g*256 + mem*16 + (l&15); k0 = kc*32 + (l>>4)*8
__global__ void pack_frag(const float* __restrict__ Wa, int da,
                          const float* __restrict__ Wb, int db,
                          int nkc, u16* __restrict__ out,
                          const float* __restrict__ bi, const float* __restrict__ bh,
                          float* __restrict__ bout)
{
    int total = 16 * nkc * 4 * 64;
    int gt = blockIdx.x * blockDim.x + threadIdx.x;
    int stride = gridDim.x * blockDim.x;
    for (int u = gt; u < total; u += stride) {
        int l = u & 63;
        int t1 = u >> 6;
        int g = t1 & 3;
        int t2 = t1 >> 2;
        int kc = t2 % nkc;
        int mem = t2 / nkc;
        int row = g * 256 + mem * 16 + (l & 15);
        int k0 = kc * 32 + ((l >> 4) << 3);
        u16x8 o;
#pragma unroll
        for (int jj = 0; jj < 8; ++jj) {
            int k = k0 + jj;
            float v = (k < da) ? Wa[(size_t)row * da + k] : Wb[(size_t)row * db + (k - da)];
            o[jj] = f2bf(v);
        }
        *(u16x8*)(out + (size_t)u * 8) = o;
    }
    if (bout && gt < 1024) bout[gt] = bi[gt] + bh[gt];
}

// ---------------- final linear ----------------
__global__ void final_linear(const float* __restrict__ latent, const float* __restrict__ W3,
                             const float* __restrict__ b3, float* __restrict__ out)
{
    int idx = blockIdx.x * blockDim.x + threadIdx.x;
    if (idx >= BATCH * 10) return;
    int bb = idx / 10, c = idx - bb * 10;
    const float* lrow = latent + (size_t)bb * 512;
    const float* wrow = W3 + (size_t)c * 512;
    float s = b3[c];
#pragma unroll 4
    for (int k = 0; k < 512; k += 4) {
        float4 lv = *(const float4*)(lrow + k);
        float4 wv = *(const float4*)(wrow + k);
        s += lv.x * wv.x + lv.y * wv.y + lv.z * wv.z + lv.w * wv.w;
    }
    out[idx] = s;
}

// ---------------- launch ----------------
extern "C" void kernel_launch(void* const* d_in, const int* in_sizes, int n_in,
                              void* d_out, int out_size, void* d_ws, size_t ws_size,
                              hipStream_t stream)
{
    (void)in_sizes; (void)n_in; (void)out_size;
    if (ws_size < WS_NEED) return;   // leaves d_out poisoned -> diagnosable as ws shortfall

    const float* xs     = (const float*)d_in[0];
    const float* Wih_f0 = (const float*)d_in[1];
    const float* Whh_f0 = (const float*)d_in[2];
    const float* bih_f0 = (const float*)d_in[3];
    const float* bhh_f0 = (const float*)d_in[4];
    const float* Wih_f1 = (const float*)d_in[5];
    const float* Whh_f1 = (const float*)d_in[6];
    const float* bih_f1 = (const float*)d_in[7];
    const float* bhh_f1 = (const float*)d_in[8];
    const float* Wih_r0 = (const float*)d_in[9];
    const float* Whh_r0 = (const float*)d_in[10];
    const float* bih_r0 = (const float*)d_in[11];
    const float* bhh_r0 = (const float*)d_in[12];
    const float* Wih_r1 = (const float*)d_in[13];
    const float* Whh_r1 = (const float*)d_in[14];
    const float* bih_r1 = (const float*)d_in[15];
    const float* bhh_r1 = (const float*)d_in[16];
    const float* W3     = (const float*)d_in[17];
    const float* b3     = (const float*)d_in[18];

    char* ws = (char*)d_ws;
    unsigned* ctl = (unsigned*)(ws + OFF_CTL);
    unsigned* h0g = (unsigned*)(ws + OFF_H0G);
    unsigned* h1g = (unsigned*)(ws + OFF_H1G);
    float* latent = (float*)(ws + OFF_LAT);
    _Float16* xp  = (_Float16*)(ws + OFF_XP);
    u16* W0xf = (u16*)(ws + OFF_W0XF);
    u16* W0xr = (u16*)(ws + OFF_W0XR);
    u16* P0f  = (u16*)(ws + OFF_P0F);
    u16* P0r  = (u16*)(ws + OFF_P0R);
    u16* P1f  = (u16*)(ws + OFF_P1F);
    u16* P1r  = (u16*)(ws + OFF_P1R);
    float* bs0f = (float*)(ws + OFF_BS0F);
    float* bs0r = (float*)(ws + OFF_BS0R);
    float* bs1f = (float*)(ws + OFF_BS1F);
    float* bs1r = (float*)(ws + OFF_BS1R);

    hipMemsetAsync(ctl, 0, 32768, stream);   // flag lines only

    pack_w<<<256, 256, 0, stream>>>(Wih_f0, 512, bih_f0, bhh_f0, W0xf, bs0f);
    pack_w<<<256, 256, 0, stream>>>(Wih_r0, 512, bih_r0, bhh_r0, W0xr, bs0r);
    pack_frag<<<64, 256, 0, stream>>>(Whh_f0, 256, Whh_f0, 0, 8,  P0f, nullptr, nullptr, nullptr);
    pack_frag<<<64, 256, 0, stream>>>(Whh_r0, 256, Whh_r0, 0, 8,  P0r, nullptr, nullptr, nullptr);
    pack_frag<<<64, 256, 0, stream>>>(Wih_f1, 256, Whh_f1, 256, 16, P1f, bih_f1, bhh_f1, bs1f);
    pack_frag<<<64, 256, 0, stream>>>(Wih_r1, 256, Whh_r1, 256, 16, P1r, bih_r1, bhh_r1, bs1r);

    xproj_gemm<<<4480, 256, 0, stream>>>(xs, W0xf, W0xr, bs0f, bs0r, xp);

    lstm_seq<<<256, 256, 0, stream>>>(xp, P0f, P0r, P1f, P1r, bs1f, bs1r,
                                      h0g, h1g, latent, ctl);

    final_linear<<<80, 256, 0, stream>>>(latent, W3, b3, (float*)d_out);
}